// Round 2
// baseline (654.909 us; speedup 1.0000x reference)
//
#include <hip/hip_runtime.h>
#include <hip/hip_bf16.h>
#include <math.h>

typedef __bf16 bf16_t;
typedef __bf16 bf16x4 __attribute__((ext_vector_type(4)));
typedef __bf16 bf16x8 __attribute__((ext_vector_type(8)));
typedef float  f32x4  __attribute__((ext_vector_type(4)));
typedef float  f32x16 __attribute__((ext_vector_type(16)));
typedef unsigned int u32x4 __attribute__((ext_vector_type(4)));

typedef const __attribute__((address_space(1))) void* gas_ptr;
typedef __attribute__((address_space(3))) void* las_ptr;

#define RD_ 64

// ---------------------------------------------------------------- fp32 -> bf16 convert
__global__ __launch_bounds__(256) void cvt_f32_bf16(const float* __restrict__ in,
                                                    bf16_t* __restrict__ out) {
  int i = (blockIdx.x * 256 + threadIdx.x) * 4;
  float4 v = *(const float4*)&in[i];
  bf16x4 w;
  w[0] = (bf16_t)v.x; w[1] = (bf16_t)v.y; w[2] = (bf16_t)v.z; w[3] = (bf16_t)v.w;
  *(bf16x4*)&out[i] = w;
}

// ---------------------------------------------------------------- transpose + convert (fp32 in)
__global__ __launch_bounds__(256) void transpose_cvt(const float* __restrict__ in,
                                                     bf16_t* __restrict__ out,
                                                     int R, int C) {
  __shared__ bf16_t t[32][33];
  int tx = threadIdx.x & 31, ty = threadIdx.x >> 5;
  int c0 = blockIdx.x * 32, r0 = blockIdx.y * 32;
#pragma unroll
  for (int i = 0; i < 4; i++)
    t[ty + 8 * i][tx] = (bf16_t)in[(size_t)(r0 + ty + 8 * i) * C + c0 + tx];
  __syncthreads();
#pragma unroll
  for (int i = 0; i < 4; i++)
    out[(size_t)(c0 + ty + 8 * i) * R + r0 + tx] = t[tx][ty + 8 * i];
}

// ---------------------------------------------------------------- bf16 transpose (for V^T)
__global__ __launch_bounds__(256) void transpose_bf16(const bf16_t* __restrict__ in,
                                                      bf16_t* __restrict__ out,
                                                      int R, int C) {
  __shared__ bf16_t t[32][33];
  int tx = threadIdx.x & 31, ty = threadIdx.x >> 5;
  int c0 = blockIdx.x * 32, r0 = blockIdx.y * 32;
#pragma unroll
  for (int i = 0; i < 4; i++)
    t[ty + 8 * i][tx] = in[(size_t)(r0 + ty + 8 * i) * C + c0 + tx];
  __syncthreads();
#pragma unroll
  for (int i = 0; i < 4; i++)
    out[(size_t)(c0 + ty + 8 * i) * R + r0 + tx] = t[tx][ty + 8 * i];
}

// ---------------------------------------------------------------- MFMA GEMM (m97 recipe)
#define GM 128
#define GN 128
#define GK 32

template <typename OutT>
__global__ __launch_bounds__(256) void gemm_bt(const bf16_t* __restrict__ A,
                                               const bf16_t* __restrict__ Bt,
                                               OutT* __restrict__ C,
                                               int M, int N, int K) {
  __shared__ bf16_t As[GM * GK];
  __shared__ bf16_t Bs[GN * GK];
  int tid  = threadIdx.x;
  int lane = tid & 63, wave = tid >> 6;
  int wm = (wave & 1) * 64, wn = (wave >> 1) * 64;
  int bm = blockIdx.x * GM, bn = blockIdx.y * GN;
  int qd = lane >> 4, lr = lane & 15;

  f32x4 acc[4][4] = {};

  int srow = wave * 16 + (lane >> 2);
  int scol = (lane & 3) * 8;
  const bf16_t* ga0 = A  + (size_t)(bm + srow) * K + scol;
  const bf16_t* ga1 = A  + (size_t)(bm + 64 + srow) * K + scol;
  const bf16_t* gb0 = Bt + (size_t)(bn + srow) * K + scol;
  const bf16_t* gb1 = Bt + (size_t)(bn + 64 + srow) * K + scol;
  las_ptr lA0 = (las_ptr)(As + wave * 512);
  las_ptr lA1 = (las_ptr)(As + 64 * 32 + wave * 512);
  las_ptr lB0 = (las_ptr)(Bs + wave * 512);
  las_ptr lB1 = (las_ptr)(Bs + 64 * 32 + wave * 512);

  for (int k0 = 0; k0 < K; k0 += GK) {
    __syncthreads();
    __builtin_amdgcn_global_load_lds((gas_ptr)(ga0 + k0), lA0, 16, 0, 0);
    __builtin_amdgcn_global_load_lds((gas_ptr)(ga1 + k0), lA1, 16, 0, 0);
    __builtin_amdgcn_global_load_lds((gas_ptr)(gb0 + k0), lB0, 16, 0, 0);
    __builtin_amdgcn_global_load_lds((gas_ptr)(gb1 + k0), lB1, 16, 0, 0);
    __syncthreads();

    bf16x8 af[4], bfr[4];
#pragma unroll
    for (int t = 0; t < 4; t++) {
      af[t]  = *(const bf16x8*)&As[(wm + t * 16 + lr) * GK + qd * 8];
      bfr[t] = *(const bf16x8*)&Bs[(wn + t * 16 + lr) * GK + qd * 8];
    }
#pragma unroll
    for (int mt = 0; mt < 4; mt++)
#pragma unroll
      for (int nt = 0; nt < 4; nt++)
        acc[mt][nt] = __builtin_amdgcn_mfma_f32_16x16x32_bf16(af[mt], bfr[nt], acc[mt][nt], 0, 0, 0);
  }

#pragma unroll
  for (int mt = 0; mt < 4; mt++) {
    int rb = bm + wm + mt * 16 + qd * 4;
#pragma unroll
    for (int nt = 0; nt < 4; nt++) {
      int cc = bn + wn + nt * 16 + lr;
#pragma unroll
      for (int r = 0; r < 4; r++)
        C[(size_t)(rb + r) * N + cc] = (OutT)acc[mt][nt][r];
    }
  }
}

// ---------------------------------------------------------------- RMSNorm + partial RoPE
template <int NHEADS, int HSTRIDE>
__global__ __launch_bounds__(256) void norm_rope(const bf16_t* __restrict__ in,
                                                 bf16_t* __restrict__ out,
                                                 const float* __restrict__ cosv,
                                                 const float* __restrict__ sinv,
                                                 const float* __restrict__ gamma) {
  int lane = threadIdx.x & 63;
  int idx  = blockIdx.x * 4 + (threadIdx.x >> 6);
  int l = idx / NHEADS, h = idx % NHEADS;
  size_t base = (size_t)l * NHEADS * HSTRIDE + (size_t)h * HSTRIDE;
  int d0 = lane * 4;

  bf16x4 raw = *(const bf16x4*)&in[base + d0];
  float x[4];
#pragma unroll
  for (int i = 0; i < 4; i++) x[i] = (float)raw[i];
  float ss = x[0] * x[0] + x[1] * x[1] + x[2] * x[2] + x[3] * x[3];
#pragma unroll
  for (int off = 32; off >= 1; off >>= 1) ss += __shfl_xor(ss, off);
  float inv = 1.0f / sqrtf(ss * (1.0f / 256.0f) + 1e-6f);

  float4 gr = *(const float4*)&gamma[d0];
  float n[4];
#pragma unroll
  for (int i = 0; i < 4; i++) n[i] = x[i] * inv * ((const float*)&gr)[i];

  float p[4];
#pragma unroll
  for (int i = 0; i < 4; i++) p[i] = __shfl_xor(n[i], 8);
  float o[4];
#pragma unroll
  for (int i = 0; i < 4; i++) o[i] = n[i];
  if (lane < 16) {
    float4 cr = *(const float4*)&cosv[(size_t)l * RD_ + d0];
    float4 sr = *(const float4*)&sinv[(size_t)l * RD_ + d0];
#pragma unroll
    for (int i = 0; i < 4; i++) {
      float rh = (lane < 8) ? -p[i] : p[i];
      o[i] = n[i] * ((const float*)&cr)[i] + rh * ((const float*)&sr)[i];
    }
  }
  bf16x4 w;
#pragma unroll
  for (int i = 0; i < 4; i++) w[i] = (bf16_t)o[i];
  *(bf16x4*)&out[base + d0] = w;
}

// ---------------------------------------------------------------- MFMA flash attention v5
// Uniform-work split-j decomposition + 2-phase double-buffered staging (T3 minimum recipe):
//  - block = 128 q-rows x 4 waves (one 32-row strip each), SHARED 32-j tile (4x reuse)
//  - j chunked at <=32 tiles (1024 j) -> 640 near-uniform blocks; fp32 partial O + l
//    to workspace; static-max softmax makes partials purely additive
//  - dbuf LDS 2x(16K K + 16K V) = 64KB -> 2 blocks/CU; per tile: issue next stage,
//    compute current, single vmcnt(0)+barrier
__global__ __launch_bounds__(256, 2) void attn_mfma(const bf16_t* __restrict__ qraw,
                                                    const bf16_t* __restrict__ kn,
                                                    const bf16_t* __restrict__ vt,
                                                    float* __restrict__ pO,
                                                    float* __restrict__ pL) {
  __shared__ __align__(16) bf16_t ks[2][32 * 256];   // 2 x 16 KB  K tile [j 32][d 256]
  __shared__ __align__(16) bf16_t vs[2][256 * 32];   // 2 x 16 KB  V^T tile [d 256][j 32]
  int tid = threadIdx.x, lane = tid & 63, wave = tid >> 6;
  int m = lane & 31, hi = lane >> 5;
  int h = blockIdx.y, g = h >> 2;

  // decode block -> (qb, chunk): chunks(qb) = qb/8 + 1, dispatched long-first
  int x = 79 - (int)blockIdx.x;
  int qb = 0, acc0 = 0;
  for (;;) { int nc = (qb >> 3) + 1; if (acc0 + nc > x) break; acc0 += nc; qb++; }
  int c = x - acc0;
  int tile0 = c * 32;
  int nt = 4 * qb + 4 - tile0; if (nt > 32) nt = 32;

  int qrow0 = qb * 128 + wave * 32;     // wave's strip base
  int qg = qrow0 + m;                    // lane's q-row
  int qmax = qrow0 + 31;

  // ---- Q fragments (B-operand of S^T = K*Q^T): lane m -> q-row, hi -> k-offset 8
  bf16x8 qf[16];
  {
    const bf16_t* qp = qraw + (size_t)(qrow0 + m) * 4096 + h * 512 + hi * 8;
#pragma unroll
    for (int kb = 0; kb < 16; kb++) qf[kb] = *(const bf16x8*)(qp + kb * 16);
  }

  // ---- swizzled LDS read offsets
  int xk = m & 7;
  int kofs[4];
#pragma unroll
  for (int b = 0; b < 4; b++)
    kofs[b] = m * 256 + ((b ^ (xk >> 1)) * 2 + (hi ^ (xk & 1))) * 8;
  int swv = (m ^ (m >> 2)) & 3;
  int vofs[2];
#pragma unroll
  for (int k2 = 0; k2 < 2; k2++)
    vofs[k2] = m * 32 + (((k2 * 2 + hi) ^ swv) * 8);

  // ---- staging source pointers (inverse swizzle folded into global addr)
  // K: seg = s*4+wave covers rows seg*2 + hi; granule = m ^ (row&7), row&7 = (wave*2+hi)&7
  const bf16_t* ksrc = kn + (size_t)(wave * 2 + hi) * 512 + g * 256
                          + (size_t)((m ^ ((wave * 2 + hi) & 7)) * 8);
  // V: seg covers d-rows seg*16 + (l>>2); granule = (l&3) ^ sw(d), sw = ((l>>2)^(l>>4))&3
  int swsrc = ((lane >> 2) ^ (lane >> 4)) & 3;
  const bf16_t* vsrc = vt + (size_t)(g * 256 + wave * 16 + (lane >> 2)) * 4096
                          + (size_t)(((lane & 3) ^ swsrc) * 8);

  f32x16 o[8] = {};
  float ladd = 0.0f;

  bf16x8 onesf;  // (unused placeholder removed semantics; l accumulated from packed words)

#define STAGE(buf, j0)                                                                  \
  do {                                                                                  \
    bf16_t* kd = &ks[buf][0] + wave * 512;                                              \
    bf16_t* vd = &vs[buf][0] + wave * 512;                                              \
    _Pragma("unroll")                                                                   \
    for (int s = 0; s < 4; s++)                                                         \
      __builtin_amdgcn_global_load_lds((gas_ptr)(ksrc + (size_t)(j0) * 512 + s * 4096), \
                                       (las_ptr)(kd + s * 2048), 16, 0, 0);             \
    _Pragma("unroll")                                                                   \
    for (int s = 0; s < 4; s++)                                                         \
      __builtin_amdgcn_global_load_lds((gas_ptr)(vsrc + (size_t)(j0) + (size_t)s * 262144), \
                                       (las_ptr)(vd + s * 2048), 16, 0, 0);             \
  } while (0)

  // prologue: stage tile 0
  STAGE(0, tile0 * 32);
  asm volatile("s_waitcnt vmcnt(0)" ::: "memory");
  __syncthreads();

  for (int t = 0; t < nt; t++) {
    int cur = t & 1;
    if (t + 1 < nt) STAGE(cur ^ 1, (tile0 + t + 1) * 32);
    int j0 = (tile0 + t) * 32;
    if (j0 <= qmax) {
      // ---- S^T = K * Q^T  (32j x 32q): acc row j = (r&3)+8*(r>>2)+4*hi, col q = m
      f32x16 sa = {};
#pragma unroll
      for (int kb = 0; kb < 16; kb++) {
        bf16x8 kf = *(const bf16x8*)&ks[cur][kofs[kb & 3] + (kb >> 2) * 64];
        sa = __builtin_amdgcn_mfma_f32_32x32x16_bf16(kf, qf[kb], sa, 0, 0, 0);
      }

      bool diag = (j0 + 31 > qrow0);
#pragma unroll
      for (int k2 = 0; k2 < 2; k2++) {
        // static-max softmax: p = exp(s/16 - 20); |s/16| <= 16 by Cauchy-Schwarz
        float pp[8];
#pragma unroll
        for (int r = 0; r < 8; r++) {
          int rr = k2 * 8 + r;
          float e = __expf(sa[rr] * 0.0625f - 20.0f);
          if (diag) {
            int jr = j0 + (rr & 3) + 8 * (rr >> 2) + 4 * hi;
            if (jr > qg) e = 0.0f;
          }
          pp[r] = e;
        }
        // pack to PV A-fragment: cvt_pk pairs + permlane32_swap (T12 recipe)
        unsigned a0, b0, a1, b1;
        asm("v_cvt_pk_bf16_f32 %0, %1, %2" : "=v"(a0) : "v"(pp[0]), "v"(pp[1]));
        asm("v_cvt_pk_bf16_f32 %0, %1, %2" : "=v"(b0) : "v"(pp[4]), "v"(pp[5]));
        asm("v_cvt_pk_bf16_f32 %0, %1, %2" : "=v"(a1) : "v"(pp[2]), "v"(pp[3]));
        asm("v_cvt_pk_bf16_f32 %0, %1, %2" : "=v"(b1) : "v"(pp[6]), "v"(pp[7]));
        asm("v_permlane32_swap_b32 %0, %1" : "+v"(a0), "+v"(b0));
        asm("v_permlane32_swap_b32 %0, %1" : "+v"(a1), "+v"(b1));
        u32x4 uw = {a0, a1, b0, b1};
        bf16x8 pa = __builtin_bit_cast(bf16x8, uw);
        // l from the rounded bf16 values (consistent with PV numerics)
#pragma unroll
        for (int i = 0; i < 4; i++) {
          unsigned w = uw[i];
          ladd += __builtin_bit_cast(float, w << 16);
          ladd += __builtin_bit_cast(float, w & 0xffff0000u);
        }
        // ---- O += P V
#pragma unroll
        for (int dt = 0; dt < 8; dt++) {
          bf16x8 vf = *(const bf16x8*)&vs[cur][vofs[k2] + dt * 1024];
          o[dt] = __builtin_amdgcn_mfma_f32_32x32x16_bf16(pa, vf, o[dt], 0, 0, 0);
        }
      }
    }
    asm volatile("s_waitcnt vmcnt(0)" ::: "memory");
    __syncthreads();
  }
#undef STAGE

  // ---- write fp32 partials (no cross-wave merge needed: waves own disjoint strips)
  int slot = h * 80 + x;
  float lo = ladd + __shfl_xor(ladd, 32);
  if (hi == 0) pL[(size_t)slot * 128 + wave * 32 + m] = lo;
  size_t ob = (size_t)slot * 32768 + (size_t)(wave * 32) * 256;
#pragma unroll
  for (int dt = 0; dt < 8; dt++)
#pragma unroll
    for (int r = 0; r < 16; r++) {
      int q = (r & 3) + 8 * (r >> 2) + 4 * hi;
      pO[ob + (size_t)q * 256 + dt * 32 + m] = o[dt][r];
    }
}

// ---------------------------------------------------------------- combine partials + gate
__global__ __launch_bounds__(256) void attn_combine(const float* __restrict__ pO,
                                                    const float* __restrict__ pL,
                                                    const bf16_t* __restrict__ qraw,
                                                    bf16_t* __restrict__ outg) {
  int qb = blockIdx.x, h = blockIdx.y;
  int g8 = qb >> 3, rr = qb & 7;
  int off = qb + 4 * g8 * (g8 - 1) + rr * g8;
  int nc = g8 + 1;
  int tid = threadIdx.x;
  int r = tid >> 1, half = tid & 1;
  int row = qb * 128 + r;
  size_t base = (size_t)(h * 80 + off);

  float lsum = 0.0f;
  for (int c = 0; c < nc; c++) lsum += pL[(base + c) * 128 + r];
  float linv = 1.0f / lsum;

  const bf16_t* gb = qraw + (size_t)row * 4096 + h * 512 + 256 + half * 128;
  bf16_t* op = outg + (size_t)row * 2048 + h * 256 + half * 128;
  size_t pbase = base * 32768 + (size_t)r * 256 + half * 128;
#pragma unroll 4
  for (int d = 0; d < 128; d += 4) {
    float a0 = 0, a1 = 0, a2 = 0, a3 = 0;
    for (int c = 0; c < nc; c++) {
      float4 v = *(const float4*)&pO[pbase + (size_t)c * 32768 + d];
      a0 += v.x; a1 += v.y; a2 += v.z; a3 += v.w;
    }
    float vv[4] = {a0, a1, a2, a3};
    bf16x4 gr = *(const bf16x4*)&gb[d];
    bf16x4 w;
#pragma unroll
    for (int i = 0; i < 4; i++) {
      float gt = (float)gr[i];
      float sg = 1.0f / (1.0f + __expf(-gt));
      w[i] = (bf16_t)(vv[i] * linv * sg);
    }
    *(bf16x4*)&op[d] = w;
  }
}

// ---------------------------------------------------------------- launch
extern "C" void kernel_launch(void* const* d_in, const int* in_sizes, int n_in,
                              void* d_out, int out_size, void* d_ws, size_t ws_size,
                              hipStream_t stream) {
  const float* x    = (const float*)d_in[0];
  const float* cosv = (const float*)d_in[1];
  const float* sinv = (const float*)d_in[2];
  // d_in[3] = mask (causal triu k=1) — deterministic, hardcoded
  const float* wq   = (const float*)d_in[4];
  const float* wk   = (const float*)d_in[5];
  const float* wv   = (const float*)d_in[6];
  const float* wo   = (const float*)d_in[7];
  const float* qg   = (const float*)d_in[8];
  const float* kg   = (const float*)d_in[9];
  float* outp = (float*)d_out;   // output is fp32

  char* ws = (char*)d_ws;
  size_t off = 0;
  auto alloc = [&](size_t bytes) { char* p = ws + off; off += (bytes + 255) & ~255ull; return p; };

  // live-through-attn region first
  bf16_t* q_raw  = (bf16_t*)alloc((size_t)4096 * 4096 * 2);
  bf16_t* k_raw  = (bf16_t*)alloc((size_t)4096 * 512 * 2);
  bf16_t* v_t    = (bf16_t*)alloc((size_t)512 * 4096 * 2);
  bf16_t* attn_g = (bf16_t*)alloc((size_t)4096 * 2048 * 2);
  bf16_t* woT    = (bf16_t*)alloc((size_t)2048 * 2048 * 2);

  // scratch region: dead before attn runs -> overlaid by partial-O buffer
  size_t scratch0 = off;
  bf16_t* x_bf = (bf16_t*)alloc((size_t)4096 * 2048 * 2);
  bf16_t* wqT  = (bf16_t*)alloc((size_t)2048 * 4096 * 2);
  bf16_t* wkT  = (bf16_t*)alloc((size_t)2048 * 512 * 2);
  bf16_t* wvT  = (bf16_t*)alloc((size_t)2048 * 512 * 2);
  bf16_t* v_b  = (bf16_t*)alloc((size_t)4096 * 512 * 2);

  float* pO = (float*)(ws + scratch0);              // 640 slots x 128 x 256 fp32 = 83.9 MB
  size_t poEnd = scratch0 + (size_t)640 * 32768 * 4;
  if (off < poEnd) off = (poEnd + 255) & ~255ull;
  float* pL = (float*)alloc((size_t)640 * 128 * 4);

  dim3 blk(256);
  cvt_f32_bf16<<<8192, blk, 0, stream>>>(x, x_bf);

  transpose_cvt<<<dim3(4096 / 32, 2048 / 32), blk, 0, stream>>>(wq, wqT, 2048, 4096);
  transpose_cvt<<<dim3(512 / 32, 2048 / 32), blk, 0, stream>>>(wk, wkT, 2048, 512);
  transpose_cvt<<<dim3(512 / 32, 2048 / 32), blk, 0, stream>>>(wv, wvT, 2048, 512);
  transpose_cvt<<<dim3(2048 / 32, 2048 / 32), blk, 0, stream>>>(wo, woT, 2048, 2048);

  gemm_bt<bf16_t><<<dim3(4096 / 128, 4096 / 128), blk, 0, stream>>>(x_bf, wqT, q_raw, 4096, 4096, 2048);
  gemm_bt<bf16_t><<<dim3(4096 / 128, 512 / 128), blk, 0, stream>>>(x_bf, wkT, k_raw, 4096, 512, 2048);
  gemm_bt<bf16_t><<<dim3(4096 / 128, 512 / 128), blk, 0, stream>>>(x_bf, wvT, v_b, 4096, 512, 2048);

  norm_rope<8, 512><<<4096 * 8 / 4, blk, 0, stream>>>(q_raw, q_raw, cosv, sinv, qg);
  norm_rope<2, 256><<<4096 * 2 / 4, blk, 0, stream>>>(k_raw, k_raw, cosv, sinv, kg);

  transpose_bf16<<<dim3(512 / 32, 4096 / 32), blk, 0, stream>>>(v_b, v_t, 4096, 512);

  attn_mfma<<<dim3(80, 8), blk, 0, stream>>>(q_raw, k_raw, v_t, pO, pL);
  attn_combine<<<dim3(32, 8), blk, 0, stream>>>(pO, pL, q_raw, attn_g);

  gemm_bt<float><<<dim3(4096 / 128, 2048 / 128), blk, 0, stream>>>(attn_g, woT, outp, 4096, 2048, 2048);
}

// Round 3
// 517.142 us; speedup vs baseline: 1.2664x; 1.2664x over previous
//
#include <hip/hip_runtime.h>
#include <hip/hip_bf16.h>
#include <math.h>

typedef __bf16 bf16_t;
typedef __bf16 bf16x4 __attribute__((ext_vector_type(4)));
typedef __bf16 bf16x8 __attribute__((ext_vector_type(8)));
typedef float  f32x4  __attribute__((ext_vector_type(4)));
typedef float  f32x16 __attribute__((ext_vector_type(16)));
typedef unsigned int u32x4 __attribute__((ext_vector_type(4)));

typedef const __attribute__((address_space(1))) void* gas_ptr;
typedef __attribute__((address_space(3))) void* las_ptr;

#define RD_ 64
#define QKVS 5120   // fused qkv row stride (4096 q+gate | 512 k | 512 v)

// ---------------------------------------------------------------- fp32 -> bf16 convert
__global__ __launch_bounds__(256) void cvt_f32_bf16(const float* __restrict__ in,
                                                    bf16_t* __restrict__ out) {
  int i = (blockIdx.x * 256 + threadIdx.x) * 4;
  float4 v = *(const float4*)&in[i];
  bf16x4 w;
  w[0] = (bf16_t)v.x; w[1] = (bf16_t)v.y; w[2] = (bf16_t)v.z; w[3] = (bf16_t)v.w;
  *(bf16x4*)&out[i] = w;
}

// ---------------------------------------------------------------- transpose + convert (fp32 in)
__global__ __launch_bounds__(256) void transpose_cvt(const float* __restrict__ in,
                                                     bf16_t* __restrict__ out,
                                                     int R, int C) {
  __shared__ bf16_t t[32][33];
  int tx = threadIdx.x & 31, ty = threadIdx.x >> 5;
  int c0 = blockIdx.x * 32, r0 = blockIdx.y * 32;
#pragma unroll
  for (int i = 0; i < 4; i++)
    t[ty + 8 * i][tx] = (bf16_t)in[(size_t)(r0 + ty + 8 * i) * C + c0 + tx];
  __syncthreads();
#pragma unroll
  for (int i = 0; i < 4; i++)
    out[(size_t)(c0 + ty + 8 * i) * R + r0 + tx] = t[tx][ty + 8 * i];
}

// ---------------------------------------------------------------- bf16 transpose (for V^T)
// in: R x (cols at stride C), out: cols x R
__global__ __launch_bounds__(256) void transpose_bf16(const bf16_t* __restrict__ in,
                                                      bf16_t* __restrict__ out,
                                                      int R, int C) {
  __shared__ bf16_t t[32][33];
  int tx = threadIdx.x & 31, ty = threadIdx.x >> 5;
  int c0 = blockIdx.x * 32, r0 = blockIdx.y * 32;
#pragma unroll
  for (int i = 0; i < 4; i++)
    t[ty + 8 * i][tx] = in[(size_t)(r0 + ty + 8 * i) * C + c0 + tx];
  __syncthreads();
#pragma unroll
  for (int i = 0; i < 4; i++)
    out[(size_t)(c0 + ty + 8 * i) * R + r0 + tx] = t[tx][ty + 8 * i];
}

// ---------------------------------------------------------------- MFMA GEMM (m97 recipe)
#define GM 128
#define GN 128
#define GK 32

template <typename OutT>
__global__ __launch_bounds__(256) void gemm_bt(const bf16_t* __restrict__ A,
                                               const bf16_t* __restrict__ Bt,
                                               OutT* __restrict__ C,
                                               int M, int N, int K) {
  __shared__ bf16_t As[GM * GK];
  __shared__ bf16_t Bs[GN * GK];
  int tid  = threadIdx.x;
  int lane = tid & 63, wave = tid >> 6;
  int wm = (wave & 1) * 64, wn = (wave >> 1) * 64;
  int bm = blockIdx.x * GM, bn = blockIdx.y * GN;
  int qd = lane >> 4, lr = lane & 15;

  f32x4 acc[4][4] = {};

  int srow = wave * 16 + (lane >> 2);
  int scol = (lane & 3) * 8;
  const bf16_t* ga0 = A  + (size_t)(bm + srow) * K + scol;
  const bf16_t* ga1 = A  + (size_t)(bm + 64 + srow) * K + scol;
  const bf16_t* gb0 = Bt + (size_t)(bn + srow) * K + scol;
  const bf16_t* gb1 = Bt + (size_t)(bn + 64 + srow) * K + scol;
  las_ptr lA0 = (las_ptr)(As + wave * 512);
  las_ptr lA1 = (las_ptr)(As + 64 * 32 + wave * 512);
  las_ptr lB0 = (las_ptr)(Bs + wave * 512);
  las_ptr lB1 = (las_ptr)(Bs + 64 * 32 + wave * 512);

  for (int k0 = 0; k0 < K; k0 += GK) {
    __syncthreads();
    __builtin_amdgcn_global_load_lds((gas_ptr)(ga0 + k0), lA0, 16, 0, 0);
    __builtin_amdgcn_global_load_lds((gas_ptr)(ga1 + k0), lA1, 16, 0, 0);
    __builtin_amdgcn_global_load_lds((gas_ptr)(gb0 + k0), lB0, 16, 0, 0);
    __builtin_amdgcn_global_load_lds((gas_ptr)(gb1 + k0), lB1, 16, 0, 0);
    __syncthreads();

    bf16x8 af[4], bfr[4];
#pragma unroll
    for (int t = 0; t < 4; t++) {
      af[t]  = *(const bf16x8*)&As[(wm + t * 16 + lr) * GK + qd * 8];
      bfr[t] = *(const bf16x8*)&Bs[(wn + t * 16 + lr) * GK + qd * 8];
    }
#pragma unroll
    for (int mt = 0; mt < 4; mt++)
#pragma unroll
      for (int nt = 0; nt < 4; nt++)
        acc[mt][nt] = __builtin_amdgcn_mfma_f32_16x16x32_bf16(af[mt], bfr[nt], acc[mt][nt], 0, 0, 0);
  }

#pragma unroll
  for (int mt = 0; mt < 4; mt++) {
    int rb = bm + wm + mt * 16 + qd * 4;
#pragma unroll
    for (int nt = 0; nt < 4; nt++) {
      int cc = bn + wn + nt * 16 + lr;
#pragma unroll
      for (int r = 0; r < 4; r++)
        C[(size_t)(rb + r) * N + cc] = (OutT)acc[mt][nt][r];
    }
  }
}

// ---------------------------------------------------------------- RMSNorm + partial RoPE
template <int NHEADS, int HSTRIDE, int RSTRIDE>
__global__ __launch_bounds__(256) void norm_rope(const bf16_t* __restrict__ in,
                                                 bf16_t* __restrict__ out,
                                                 const float* __restrict__ cosv,
                                                 const float* __restrict__ sinv,
                                                 const float* __restrict__ gamma) {
  int lane = threadIdx.x & 63;
  int idx  = blockIdx.x * 4 + (threadIdx.x >> 6);
  int l = idx / NHEADS, h = idx % NHEADS;
  size_t base = (size_t)l * RSTRIDE + (size_t)h * HSTRIDE;
  int d0 = lane * 4;

  bf16x4 raw = *(const bf16x4*)&in[base + d0];
  float x[4];
#pragma unroll
  for (int i = 0; i < 4; i++) x[i] = (float)raw[i];
  float ss = x[0] * x[0] + x[1] * x[1] + x[2] * x[2] + x[3] * x[3];
#pragma unroll
  for (int off = 32; off >= 1; off >>= 1) ss += __shfl_xor(ss, off);
  float inv = 1.0f / sqrtf(ss * (1.0f / 256.0f) + 1e-6f);

  float4 gr = *(const float4*)&gamma[d0];
  float n[4];
#pragma unroll
  for (int i = 0; i < 4; i++) n[i] = x[i] * inv * ((const float*)&gr)[i];

  float p[4];
#pragma unroll
  for (int i = 0; i < 4; i++) p[i] = __shfl_xor(n[i], 8);
  float o[4];
#pragma unroll
  for (int i = 0; i < 4; i++) o[i] = n[i];
  if (lane < 16) {
    float4 cr = *(const float4*)&cosv[(size_t)l * RD_ + d0];
    float4 sr = *(const float4*)&sinv[(size_t)l * RD_ + d0];
#pragma unroll
    for (int i = 0; i < 4; i++) {
      float rh = (lane < 8) ? -p[i] : p[i];
      o[i] = n[i] * ((const float*)&cr)[i] + rh * ((const float*)&sr)[i];
    }
  }
  bf16x4 w;
#pragma unroll
  for (int i = 0; i < 4; i++) w[i] = (bf16_t)o[i];
  *(bf16x4*)&out[base + d0] = w;
}

// ---------------------------------------------------------------- MFMA flash attention v6
// XCD-pinned split-j + direct-final path:
//  - 1-D grid 384; h = b%8 -> all of a head's blocks land on one XCD (round-robin
//    heuristic) so that group's K+V (4 MB) stays L2-resident -> staging drain = L2 hit
//  - 64-tile (2048-j) chunks: qb 0..15 single chunk -> gated bf16 output DIRECT
//    (no partials); qb 16..31 two chunks -> fp32 partials (33.6 MB, was 84)
//  - 2-phase dbuf LDS (64 KB), shared 32-j tile consumed by all 4 waves
__global__ __launch_bounds__(256, 2) void attn_mfma(const bf16_t* __restrict__ qraw,
                                                    const bf16_t* __restrict__ kn,
                                                    const bf16_t* __restrict__ vt,
                                                    bf16_t* __restrict__ outg,
                                                    float* __restrict__ pO,
                                                    float* __restrict__ pL) {
  __shared__ __align__(16) bf16_t ks[2][32 * 256];   // 2 x 16 KB  K tile [j 32][d 256]
  __shared__ __align__(16) bf16_t vs[2][256 * 32];   // 2 x 16 KB  V^T tile [d 256][j 32]
  int tid = threadIdx.x, lane = tid & 63, wave = tid >> 6;
  int m = lane & 31, hi = lane >> 5;
  int b = blockIdx.x;
  int h = b & 7, g = h >> 2, i = b >> 3;

  // decode i -> (qb, tile0, nt, fin), long-first: i<16 = 64-tile A-chunks of qb 31..16;
  // then pairs (single-chunk final qb 15..0, B-chunk qb 31..16) descending by size
  int qb, tile0, nt; bool fin = false;
  if (i < 16) { qb = 31 - i; tile0 = 0; nt = 64; }
  else {
    int u = (i - 16) >> 1;
    if (((i - 16) & 1) == 0) { qb = 15 - u; tile0 = 0; nt = 4 * qb + 4; fin = true; }
    else                     { qb = 31 - u; tile0 = 64; nt = 4 * qb + 4 - 64; }
  }

  int qrow0 = qb * 128 + wave * 32;     // wave's strip base
  int qg = qrow0 + m;                    // lane's q-row
  int qmax = qrow0 + 31;

  // ---- Q fragments (B-operand of S^T = K*Q^T): lane m -> q-row, hi -> k-offset 8
  bf16x8 qf[16];
  {
    const bf16_t* qp = qraw + (size_t)(qrow0 + m) * QKVS + h * 512 + hi * 8;
#pragma unroll
    for (int kb = 0; kb < 16; kb++) qf[kb] = *(const bf16x8*)(qp + kb * 16);
  }

  // ---- swizzled LDS read offsets
  int xk = m & 7;
  int kofs[4];
#pragma unroll
  for (int bb = 0; bb < 4; bb++)
    kofs[bb] = m * 256 + ((bb ^ (xk >> 1)) * 2 + (hi ^ (xk & 1))) * 8;
  int swv = (m ^ (m >> 2)) & 3;
  int vofs[2];
#pragma unroll
  for (int k2 = 0; k2 < 2; k2++)
    vofs[k2] = m * 32 + (((k2 * 2 + hi) ^ swv) * 8);

  // ---- staging source pointers (inverse swizzle folded into global addr)
  const bf16_t* ksrc = kn + (size_t)(wave * 2 + hi) * QKVS + g * 256
                          + (size_t)((m ^ ((wave * 2 + hi) & 7)) * 8);
  int swsrc = ((lane >> 2) ^ (lane >> 4)) & 3;
  const bf16_t* vsrc = vt + (size_t)(g * 256 + wave * 16 + (lane >> 2)) * 4096
                          + (size_t)(((lane & 3) ^ swsrc) * 8);

  f32x16 o[8] = {};
  float ladd = 0.0f;

#define STAGE(buf, j0)                                                                      \
  do {                                                                                      \
    bf16_t* kd = &ks[buf][0] + wave * 512;                                                  \
    bf16_t* vd = &vs[buf][0] + wave * 512;                                                  \
    _Pragma("unroll")                                                                       \
    for (int s = 0; s < 4; s++)                                                             \
      __builtin_amdgcn_global_load_lds((gas_ptr)(ksrc + (size_t)(j0) * QKVS + s * 8 * QKVS),\
                                       (las_ptr)(kd + s * 2048), 16, 0, 0);                 \
    _Pragma("unroll")                                                                       \
    for (int s = 0; s < 4; s++)                                                             \
      __builtin_amdgcn_global_load_lds((gas_ptr)(vsrc + (size_t)(j0) + (size_t)s * 262144), \
                                       (las_ptr)(vd + s * 2048), 16, 0, 0);                 \
  } while (0)

  // prologue: stage tile 0
  STAGE(0, tile0 * 32);
  asm volatile("s_waitcnt vmcnt(0)" ::: "memory");
  __syncthreads();

  for (int t = 0; t < nt; t++) {
    int cur = t & 1;
    if (t + 1 < nt) STAGE(cur ^ 1, (tile0 + t + 1) * 32);
    int j0 = (tile0 + t) * 32;
    if (j0 <= qmax) {
      // ---- S^T = K * Q^T  (32j x 32q): acc row j = (r&3)+8*(r>>2)+4*hi, col q = m
      f32x16 sa = {};
#pragma unroll
      for (int kb = 0; kb < 16; kb++) {
        bf16x8 kf = *(const bf16x8*)&ks[cur][kofs[kb & 3] + (kb >> 2) * 64];
        sa = __builtin_amdgcn_mfma_f32_32x32x16_bf16(kf, qf[kb], sa, 0, 0, 0);
      }

      bool diag = (j0 + 31 > qrow0);
#pragma unroll
      for (int k2 = 0; k2 < 2; k2++) {
        // static-max softmax: p = exp(s/16 - 20); |s/16| <= 16 by Cauchy-Schwarz
        float pp[8];
#pragma unroll
        for (int r = 0; r < 8; r++) {
          int rr = k2 * 8 + r;
          float e = __expf(sa[rr] * 0.0625f - 20.0f);
          if (diag) {
            int jr = j0 + (rr & 3) + 8 * (rr >> 2) + 4 * hi;
            if (jr > qg) e = 0.0f;
          }
          pp[r] = e;
        }
        // pack to PV A-fragment: cvt_pk pairs + permlane32_swap (T12 recipe)
        unsigned a0, b0, a1, b1;
        asm("v_cvt_pk_bf16_f32 %0, %1, %2" : "=v"(a0) : "v"(pp[0]), "v"(pp[1]));
        asm("v_cvt_pk_bf16_f32 %0, %1, %2" : "=v"(b0) : "v"(pp[4]), "v"(pp[5]));
        asm("v_cvt_pk_bf16_f32 %0, %1, %2" : "=v"(a1) : "v"(pp[2]), "v"(pp[3]));
        asm("v_cvt_pk_bf16_f32 %0, %1, %2" : "=v"(b1) : "v"(pp[6]), "v"(pp[7]));
        asm("v_permlane32_swap_b32 %0, %1" : "+v"(a0), "+v"(b0));
        asm("v_permlane32_swap_b32 %0, %1" : "+v"(a1), "+v"(b1));
        u32x4 uw = {a0, a1, b0, b1};
        bf16x8 pa = __builtin_bit_cast(bf16x8, uw);
        // l from the rounded bf16 values (consistent with PV numerics)
#pragma unroll
        for (int ii = 0; ii < 4; ii++) {
          unsigned w = uw[ii];
          ladd += __builtin_bit_cast(float, w << 16);
          ladd += __builtin_bit_cast(float, w & 0xffff0000u);
        }
        // ---- O += P V
#pragma unroll
        for (int dt = 0; dt < 8; dt++) {
          bf16x8 vf = *(const bf16x8*)&vs[cur][vofs[k2] + dt * 1024];
          o[dt] = __builtin_amdgcn_mfma_f32_32x32x16_bf16(pa, vf, o[dt], 0, 0, 0);
        }
      }
    }
    asm volatile("s_waitcnt vmcnt(0)" ::: "memory");
    __syncthreads();
  }
#undef STAGE

  float lo = ladd + __shfl_xor(ladd, 32);   // l per q-row (uniform across hi)

  if (fin) {
    // ---- direct path: 1/l + sigmoid gate + bf16 store
    float linv[16];
#pragma unroll
    for (int r = 0; r < 16; r++)
      linv[r] = 1.0f / __shfl(lo, (r & 3) + 8 * (r >> 2) + 4 * hi, 64);
    const bf16_t* gb = qraw + (size_t)qrow0 * QKVS + h * 512 + 256;
#pragma unroll
    for (int dt = 0; dt < 8; dt++)
#pragma unroll
      for (int r = 0; r < 16; r++) {
        int q = (r & 3) + 8 * (r >> 2) + 4 * hi;
        int d = dt * 32 + m;
        float gt = (float)gb[(size_t)q * QKVS + d];
        float sg = 1.0f / (1.0f + __expf(-gt));
        outg[(size_t)(qrow0 + q) * 2048 + h * 256 + d] = (bf16_t)(o[dt][r] * linv[r] * sg);
      }
  } else {
    // ---- fp32 partials (qb 16..31, 2 chunks): slot = (h*16 + qb-16)*2 + chunkid
    int sidx = (h * 16 + (qb - 16)) * 2 + (tile0 ? 1 : 0);
    if (hi == 0) pL[(size_t)sidx * 128 + wave * 32 + m] = lo;
    size_t ob = (size_t)sidx * 32768 + (size_t)(wave * 32) * 256;
#pragma unroll
    for (int dt = 0; dt < 8; dt++)
#pragma unroll
      for (int r = 0; r < 16; r++) {
        int q = (r & 3) + 8 * (r >> 2) + 4 * hi;
        pO[ob + (size_t)q * 256 + dt * 32 + m] = o[dt][r];
      }
  }
}

// ---------------------------------------------------------------- combine 2 partials + gate
// 1-D grid 128, h = b%8 (same XCD as writer -> partials mostly L2-resident)
__global__ __launch_bounds__(256) void attn_combine(const float* __restrict__ pO,
                                                    const float* __restrict__ pL,
                                                    const bf16_t* __restrict__ qkv,
                                                    bf16_t* __restrict__ outg) {
  int b = blockIdx.x;
  int h = b & 7, qbc = 16 + (b >> 3);
  int tid = threadIdx.x;
  int r = tid >> 1, half = tid & 1;
  int row = qbc * 128 + r;
  size_t sA = ((size_t)h * 16 + (qbc - 16)) * 2;

  float lsum = pL[sA * 128 + r] + pL[(sA + 1) * 128 + r];
  float linv = 1.0f / lsum;

  const bf16_t* gb = qkv + (size_t)row * QKVS + h * 512 + 256 + half * 128;
  bf16_t* op = outg + (size_t)row * 2048 + h * 256 + half * 128;
  size_t p0 = sA * 32768 + (size_t)r * 256 + half * 128;
  size_t p1 = p0 + 32768;
#pragma unroll 4
  for (int d = 0; d < 128; d += 4) {
    float4 a = *(const float4*)&pO[p0 + d];
    float4 c = *(const float4*)&pO[p1 + d];
    bf16x4 gr = *(const bf16x4*)&gb[d];
    float vv[4] = {a.x + c.x, a.y + c.y, a.z + c.z, a.w + c.w};
    bf16x4 w;
#pragma unroll
    for (int i = 0; i < 4; i++) {
      float sg = 1.0f / (1.0f + __expf(-(float)gr[i]));
      w[i] = (bf16_t)(vv[i] * linv * sg);
    }
    *(bf16x4*)&op[d] = w;
  }
}

// ---------------------------------------------------------------- launch
extern "C" void kernel_launch(void* const* d_in, const int* in_sizes, int n_in,
                              void* d_out, int out_size, void* d_ws, size_t ws_size,
                              hipStream_t stream) {
  const float* x    = (const float*)d_in[0];
  const float* cosv = (const float*)d_in[1];
  const float* sinv = (const float*)d_in[2];
  // d_in[3] = mask (causal triu k=1) — deterministic, hardcoded
  const float* wq   = (const float*)d_in[4];
  const float* wk   = (const float*)d_in[5];
  const float* wv   = (const float*)d_in[6];
  const float* wo   = (const float*)d_in[7];
  const float* qg   = (const float*)d_in[8];
  const float* kg   = (const float*)d_in[9];
  float* outp = (float*)d_out;   // output is fp32

  char* ws = (char*)d_ws;
  size_t off = 0;
  auto alloc = [&](size_t bytes) { char* p = ws + off; off += (bytes + 255) & ~255ull; return p; };

  // live-through-attn region
  bf16_t* qkv_raw = (bf16_t*)alloc((size_t)4096 * QKVS * 2);   // 41.9 MB
  bf16_t* v_t     = (bf16_t*)alloc((size_t)512 * 4096 * 2);    // 4 MB
  bf16_t* attn_g  = (bf16_t*)alloc((size_t)4096 * 2048 * 2);   // 16 MB
  bf16_t* woT     = (bf16_t*)alloc((size_t)2048 * 2048 * 2);   // 8 MB

  // scratch region: dead before attn -> overlaid by partial-O buffer
  size_t scratch0 = off;
  bf16_t* x_bf  = (bf16_t*)alloc((size_t)4096 * 2048 * 2);     // 16 MB
  bf16_t* wqkvT = (bf16_t*)alloc((size_t)QKVS * 2048 * 2);     // 21 MB

  float* pO = (float*)(ws + scratch0);                         // 256 x 128 x 256 f32 = 33.6 MB
  size_t poEnd = scratch0 + (size_t)256 * 32768 * 4;
  if (off < poEnd) off = (poEnd + 255) & ~255ull;
  float* pL = (float*)alloc((size_t)256 * 128 * 4);

  dim3 blk(256);
  cvt_f32_bf16<<<8192, blk, 0, stream>>>(x, x_bf);

  transpose_cvt<<<dim3(4096 / 32, 2048 / 32), blk, 0, stream>>>(wq, wqkvT, 2048, 4096);
  transpose_cvt<<<dim3(512 / 32, 2048 / 32), blk, 0, stream>>>(wk, wqkvT + (size_t)4096 * 2048, 2048, 512);
  transpose_cvt<<<dim3(512 / 32, 2048 / 32), blk, 0, stream>>>(wv, wqkvT + (size_t)4608 * 2048, 2048, 512);
  transpose_cvt<<<dim3(2048 / 32, 2048 / 32), blk, 0, stream>>>(wo, woT, 2048, 2048);

  // fused QKV projection: 4096 x 5120 x 2048, 1280 blocks
  gemm_bt<bf16_t><<<dim3(4096 / 128, QKVS / 128), blk, 0, stream>>>(x_bf, wqkvT, qkv_raw, 4096, QKVS, 2048);

  norm_rope<8, 512, QKVS><<<4096 * 8 / 4, blk, 0, stream>>>(qkv_raw, qkv_raw, cosv, sinv, qg);
  norm_rope<2, 256, QKVS><<<4096 * 2 / 4, blk, 0, stream>>>(qkv_raw + 4096, qkv_raw + 4096, cosv, sinv, kg);

  transpose_bf16<<<dim3(512 / 32, 4096 / 32), blk, 0, stream>>>(qkv_raw + 4608, v_t, 4096, QKVS);

  attn_mfma<<<dim3(384), blk, 0, stream>>>(qkv_raw, qkv_raw + 4096, v_t, attn_g, pO, pL);
  attn_combine<<<dim3(128), blk, 0, stream>>>(pO, pL, qkv_raw, attn_g);

  gemm_bt<float><<<dim3(4096 / 128, 2048 / 128), blk, 0, stream>>>(attn_g, woT, outp, 4096, 2048, 2048);
}